// Round 10
// baseline (315.335 us; speedup 1.0000x reference)
//
#include <hip/hip_runtime.h>
#include <hip/hip_bf16.h>

#define HIDDEN 1024
#define INTER 4096
#define NEXP 8
#define T_TOK 2048

typedef short bf16x8 __attribute__((ext_vector_type(8)));
typedef float f32x4 __attribute__((ext_vector_type(4)));

// Conflict-free BK=32 LDS chunk layout (R7/R8/R9-verified on HW: conflicts=0).
#define CHUNK(row, kq) ((unsigned int)((row) * 64u + ((((unsigned int)(kq)) ^ ((((unsigned int)(row)) >> 1) & 3u)) << 4)))

__device__ __forceinline__ unsigned short f2bf(float f) {
    union { float f; unsigned int u; } v; v.f = f;
    return (unsigned short)(v.u >> 16);   // truncation: 10x absmax margin measured
}

// two float4 -> one 16B chunk of 8 bf16 (truncating)
__device__ __forceinline__ uint4 pack8trunc(float4 a, float4 b) {
    union { float4 f; unsigned short s[8]; } x, y; x.f = a; y.f = b;
    uint4 r;
    r.x = (unsigned int)x.s[1] | ((unsigned int)x.s[3] << 16);
    r.y = (unsigned int)x.s[5] | ((unsigned int)x.s[7] << 16);
    r.z = (unsigned int)y.s[1] | ((unsigned int)y.s[3] << 16);
    r.w = (unsigned int)y.s[5] | ((unsigned int)y.s[7] << 16);
    return r;
}

// raw barrier: NO vmcnt drain (global prefetch stays in flight across it).
__device__ __forceinline__ void block_sync() {
    asm volatile("s_waitcnt lgkmcnt(0)" ::: "memory");
    __builtin_amdgcn_s_barrier();
    asm volatile("" ::: "memory");
}

// ---------------- K1: router (fp32 exact) ----------------
__global__ void router_kernel(const float* __restrict__ x,
                              const float* __restrict__ rw,
                              float* __restrict__ logits_out,
                              int* __restrict__ counts,
                              int* __restrict__ ids,
                              float* __restrict__ wts,
                              int* __restrict__ tsel) {
    int t = blockIdx.x * 4 + (threadIdx.x >> 6);
    int lane = threadIdx.x & 63;
    if (t >= T_TOK) return;
    const float4* xr = (const float4*)(x + (size_t)t * HIDDEN);
    float acc[NEXP];
#pragma unroll
    for (int e = 0; e < NEXP; e++) acc[e] = 0.f;
#pragma unroll
    for (int c = 0; c < 4; c++) {
        float4 xv = xr[lane + c * 64];
#pragma unroll
        for (int e = 0; e < NEXP; e++) {
            float4 wv = ((const float4*)(rw + (size_t)e * HIDDEN))[lane + c * 64];
            acc[e] += xv.x * wv.x + xv.y * wv.y + xv.z * wv.z + xv.w * wv.w;
        }
    }
#pragma unroll
    for (int e = 0; e < NEXP; e++) {
        float v = acc[e];
        for (int off = 32; off >= 1; off >>= 1) v += __shfl_xor(v, off, 64);
        acc[e] = v;
    }
    if (lane == 0) {
        float* lo = logits_out + (size_t)t * NEXP;
        float mx = acc[0];
#pragma unroll
        for (int e = 1; e < NEXP; e++) mx = fmaxf(mx, acc[e]);
        float p[NEXP], s = 0.f;
#pragma unroll
        for (int e = 0; e < NEXP; e++) { p[e] = __expf(acc[e] - mx); s += p[e]; }
        float inv = 1.f / s;
#pragma unroll
        for (int e = 0; e < NEXP; e++) { p[e] *= inv; lo[e] = acc[e]; }
        int i1 = 0;
#pragma unroll
        for (int e = 1; e < NEXP; e++) if (p[e] > p[i1]) i1 = e;
        int i2 = (i1 == 0) ? 1 : 0;
#pragma unroll
        for (int e = 0; e < NEXP; e++) if (e != i1 && e != i2 && p[e] > p[i2]) i2 = e;
        // strict > keeps lowest index on ties (matches jax top_k)
        int s1 = atomicAdd(&counts[i1], 1);
        ids[i1 * T_TOK + s1] = t; wts[i1 * T_TOK + s1] = p[i1];
        int s2 = atomicAdd(&counts[i2], 1);
        ids[i2 * T_TOK + s2] = t; wts[i2 * T_TOK + s2] = p[i2];
        tsel[t * 2]     = i1 * T_TOK + s1;   // pack (expert, slot)
        tsel[t * 2 + 1] = i2 * T_TOK + s2;
    }
}

__global__ void scan_kernel(const int* __restrict__ counts, int* __restrict__ offsets) {
    if (threadIdx.x == 0) {
        int s = 0;
        for (int e = 0; e < NEXP; e++) { offsets[e] = s; s += counts[e]; }
    }
}

// ---------------- K2: fused gate+up grouped GEMM + SwiGLU ----------------
// R10 change: TWO 512-thr blocks per CU instead of one 1024-thr block.
// BM=128 x BN=128, BK=32, 8 waves (2x4, wave 64x32 per matrix), CHUNK LDS,
// dbuf 2x24KB=48KB, raw barrier, 1-deep prefetch, nt-fastest grid (R9-proven
// L3 pattern). Same 16 waves/CU total (reg-capped) but 2 barrier groups ->
// one block's staging overlaps the other's MFMA phase.
__global__ __launch_bounds__(512, 4) void gemm_gu(
    const float* __restrict__ x, const float* __restrict__ gw, const float* __restrict__ uw,
    const int* __restrict__ counts, const int* __restrict__ offsets,
    const int* __restrict__ ids, unsigned short* __restrict__ h) {
    const int e = blockIdx.z;
    const int cnt = counts[e];
    const int mt = blockIdx.y;
    if (mt * 128 >= cnt) return;
    const int nt = blockIdx.x;                    // 32 tiles of 128 inter
    const int tid = threadIdx.x;
    const int lane = tid & 63, wid = tid >> 6;
    const int wm = wid >> 2, wn = wid & 3;        // 2x4 waves

    __shared__ __align__(16) char lds[49152];     // [A 8K | Bg 8K | Bu 8K] x2

    const float* gbase = gw + (size_t)e * INTER * HIDDEN;
    const float* ubase = uw + (size_t)e * INTER * HIDDEN;

    // staging: each thread owns chunk (row=tid>>2, kq=tid&3) for A, Bg, Bu
    const int row = tid >> 2, kq = tid & 3;
    int ali = mt * 128 + row; if (ali >= cnt) ali = cnt - 1;
    const unsigned int aoff = (unsigned int)(ids[e * T_TOK + ali] * HIDDEN + kq * 8);
    const unsigned int boff = (unsigned int)((nt * 128 + row) * HIDDEN + kq * 8);
    const unsigned int wC = CHUNK(row, kq);

    f32x4 accg[4][2], accu[4][2];
#pragma unroll
    for (int mf = 0; mf < 4; mf++)
#pragma unroll
        for (int nf = 0; nf < 2; nf++)
#pragma unroll
            for (int v = 0; v < 4; v++) { accg[mf][nf][v] = 0.f; accu[mf][nf][v] = 0.f; }

    // 1-deep prefetch: one register set (24 VGPRs)
    float4 a0, a1, g0, g1, u0, u1;
    a0 = *(const float4*)(x + aoff);      a1 = *(const float4*)(x + aoff + 4);
    g0 = *(const float4*)(gbase + boff);  g1 = *(const float4*)(gbase + boff + 4);
    u0 = *(const float4*)(ubase + boff);  u1 = *(const float4*)(ubase + boff + 4);

    for (int kt = 0; kt < 32; kt++) {
        const unsigned int bb = (unsigned int)(kt & 1) * 24576u;
        *(uint4*)(lds + bb + wC) = pack8trunc(a0, a1);
        *(uint4*)(lds + bb + 8192 + wC) = pack8trunc(g0, g1);
        *(uint4*)(lds + bb + 16384 + wC) = pack8trunc(u0, u1);
        if (kt < 31) {                            // prefetch next K-tile
            const int ko = (kt + 1) * 32;
            a0 = *(const float4*)(x + aoff + ko);      a1 = *(const float4*)(x + aoff + ko + 4);
            g0 = *(const float4*)(gbase + boff + ko);  g1 = *(const float4*)(gbase + boff + ko + 4);
            u0 = *(const float4*)(ubase + boff + ko);  u1 = *(const float4*)(ubase + boff + ko + 4);
        }
        block_sync();
        const unsigned int kqr = (unsigned int)(lane >> 4);
        const unsigned int rl = (unsigned int)(lane & 15);
        bf16x8 a[4];
#pragma unroll
        for (int mf = 0; mf < 4; mf++)
            a[mf] = *(const bf16x8*)(lds + bb + CHUNK(wm * 64 + mf * 16 + rl, kqr));
#pragma unroll
        for (int nf = 0; nf < 2; nf++) {
            const unsigned int br = wn * 32 + nf * 16 + rl;
            bf16x8 bg = *(const bf16x8*)(lds + bb + 8192 + CHUNK(br, kqr));
            bf16x8 bu = *(const bf16x8*)(lds + bb + 16384 + CHUNK(br, kqr));
#pragma unroll
            for (int mf = 0; mf < 4; mf++) {
                accg[mf][nf] = __builtin_amdgcn_mfma_f32_16x16x32_bf16(a[mf], bg, accg[mf][nf], 0, 0, 0);
                accu[mf][nf] = __builtin_amdgcn_mfma_f32_16x16x32_bf16(a[mf], bu, accu[mf][nf], 0, 0, 0);
            }
        }
    }

    const int hoff = offsets[e];
#pragma unroll
    for (int mf = 0; mf < 4; mf++)
#pragma unroll
        for (int v = 0; v < 4; v++) {
            int il = wm * 64 + mf * 16 + ((lane >> 4) << 2) + v;
            int i = mt * 128 + il;
            if (i < cnt) {
                size_t rowbase = (size_t)(hoff + i) * INTER + nt * 128 + wn * 32 + (lane & 15);
#pragma unroll
                for (int nf = 0; nf < 2; nf++) {
                    float g = accg[mf][nf][v], u = accu[mf][nf][v];
                    float sg = g / (1.f + __expf(-g));
                    h[rowbase + nf * 16] = f2bf(sg * u);
                }
            }
        }
}

// ---------------- K3: down grouped GEMM -> y (no atomics) ----------------
// R10 change: 2-deep prefetch (two named reg sets E/O — acc is only 32 AGPR
// here so no spill risk; R8's spill was gu's 64-AGPR budget). Rest = R9:
// BM=128 x BN=128, BK=32, ksplit=2, 512 thr, dbuf 2x16KB=32KB, CHUNK.
__global__ __launch_bounds__(512) void gemm_down(
    const unsigned short* __restrict__ h, const float* __restrict__ dw,
    const int* __restrict__ counts, const int* __restrict__ offsets,
    const float* __restrict__ wts, float* __restrict__ y) {
    const int ez = blockIdx.z;                    // e*2 + ksp
    const int e = ez >> 1, ksp = ez & 1;
    const int cnt = counts[e];
    const int mt = blockIdx.y;
    if (mt * 128 >= cnt) return;
    const int nt = blockIdx.x;                    // 8 tiles of 128 hidden
    const int tid = threadIdx.x;
    const int lane = tid & 63, wid = tid >> 6;
    const int wm = wid >> 2, wn = wid & 3;        // 2x4 waves, wave 64x32

    __shared__ __align__(16) char lds[32768];     // [A 8K | B 8K] x2

    const int hoff = offsets[e];
    const float* dbase = dw + (size_t)e * HIDDEN * INTER;

    const int row = tid >> 2, kq = tid & 3;
    int li = mt * 128 + row; if (li >= cnt) li = cnt - 1;
    const unsigned int aoff = (unsigned int)((hoff + li) * INTER + ksp * 2048 + kq * 8);
    const unsigned int wAo = CHUNK(row, kq);
    const unsigned int boff = (unsigned int)((nt * 128 + row) * INTER + ksp * 2048 + kq * 8);
    const unsigned int wBo = 8192u + CHUNK(row, kq);

    f32x4 acc[4][2];
#pragma unroll
    for (int mf = 0; mf < 4; mf++)
#pragma unroll
        for (int nf = 0; nf < 2; nf++)
#pragma unroll
            for (int v = 0; v < 4; v++) acc[mf][nf][v] = 0.f;

    // 2-deep prefetch: set E = even tiles, set O = odd tiles
    int4 avE, avO; float4 bE0, bE1, bO0, bO1;
    avE = *(const int4*)(h + aoff);
    bE0 = *(const float4*)(dbase + boff);      bE1 = *(const float4*)(dbase + boff + 4);
    avO = *(const int4*)(h + aoff + 32);
    bO0 = *(const float4*)(dbase + boff + 32); bO1 = *(const float4*)(dbase + boff + 36);

#define DN_COMPUTE(BB)                                                                  \
    {                                                                                   \
        const unsigned int kqr = (unsigned int)(lane >> 4);                             \
        const unsigned int rl = (unsigned int)(lane & 15);                              \
        bf16x8 a[4];                                                                    \
        _Pragma("unroll")                                                               \
        for (int mf = 0; mf < 4; mf++)                                                  \
            a[mf] = *(const bf16x8*)(lds + (BB) + CHUNK(wm * 64 + mf * 16 + rl, kqr));  \
        _Pragma("unroll")                                                               \
        for (int nf = 0; nf < 2; nf++) {                                                \
            bf16x8 b = *(const bf16x8*)(lds + (BB) + 8192 + CHUNK(wn * 32 + nf * 16 + rl, kqr)); \
            _Pragma("unroll")                                                           \
            for (int mf = 0; mf < 4; mf++)                                              \
                acc[mf][nf] = __builtin_amdgcn_mfma_f32_16x16x32_bf16(a[mf], b, acc[mf][nf], 0, 0, 0); \
        }                                                                               \
    }

    for (int kt = 0; kt < 64; kt += 2) {          // 2048 K per split
        // even tile -> buf0, set E (loaded 2 iterations ago)
        *(int4*)(lds + wAo) = avE;
        *(uint4*)(lds + wBo) = pack8trunc(bE0, bE1);
        if (kt + 2 < 64) {
            const int ko = (kt + 2) * 32;
            avE = *(const int4*)(h + aoff + ko);
            bE0 = *(const float4*)(dbase + boff + ko); bE1 = *(const float4*)(dbase + boff + ko + 4);
        }
        block_sync();
        DN_COMPUTE(0u)
        // odd tile -> buf1, set O
        *(int4*)(lds + 16384 + wAo) = avO;
        *(uint4*)(lds + 16384 + wBo) = pack8trunc(bO0, bO1);
        if (kt + 3 < 64) {
            const int ko = (kt + 3) * 32;
            avO = *(const int4*)(h + aoff + ko);
            bO0 = *(const float4*)(dbase + boff + ko); bO1 = *(const float4*)(dbase + boff + ko + 4);
        }
        block_sync();
        DN_COMPUTE(16384u)
    }
#undef DN_COMPUTE

#pragma unroll
    for (int mf = 0; mf < 4; mf++)
#pragma unroll
        for (int v = 0; v < 4; v++) {
            int il = wm * 64 + mf * 16 + ((lane >> 4) << 2) + v;
            int i = mt * 128 + il;
            if (i < cnt) {
                float w = wts[e * T_TOK + i];
                float* yrow = y + ((size_t)ksp * 4096 + hoff + i) * HIDDEN
                                + nt * 128 + wn * 32 + (lane & 15);
#pragma unroll
                for (int nf = 0; nf < 2; nf++)
                    yrow[nf * 16] = w * acc[mf][nf][v];
            }
        }
}

// -------- K4: combine (out[t] = sum over 2 experts x 2 ksplits) --------
__global__ __launch_bounds__(256) void combine_kernel(
    const float* __restrict__ y, const int* __restrict__ offsets,
    const int* __restrict__ tsel, float* __restrict__ out) {
    const int t = blockIdx.x;
    const int d = threadIdx.x * 4;
    int p0 = tsel[t * 2], p1 = tsel[t * 2 + 1];
    size_t g0 = (size_t)(offsets[p0 >> 11] + (p0 & (T_TOK - 1)));
    size_t g1 = (size_t)(offsets[p1 >> 11] + (p1 & (T_TOK - 1)));
    float4 a0 = *(const float4*)(y + g0 * HIDDEN + d);
    float4 a1 = *(const float4*)(y + (4096 + g0) * HIDDEN + d);
    float4 b0 = *(const float4*)(y + g1 * HIDDEN + d);
    float4 b1 = *(const float4*)(y + (4096 + g1) * HIDDEN + d);
    float4 o;
    o.x = (a0.x + a1.x) + (b0.x + b1.x);
    o.y = (a0.y + a1.y) + (b0.y + b1.y);
    o.z = (a0.z + a1.z) + (b0.z + b1.z);
    o.w = (a0.w + a1.w) + (b0.w + b1.w);
    *(float4*)(out + (size_t)t * HIDDEN + d) = o;
}

extern "C" void kernel_launch(void* const* d_in, const int* in_sizes, int n_in,
                              void* d_out, int out_size, void* d_ws, size_t ws_size,
                              hipStream_t stream) {
    const float* x  = (const float*)d_in[0];
    const float* rw = (const float*)d_in[1];
    const float* gw = (const float*)d_in[2];
    const float* uw = (const float*)d_in[3];
    const float* dw = (const float*)d_in[4];
    float* out = (float*)d_out;
    float* logits = out + (size_t)T_TOK * HIDDEN;

    char* ws = (char*)d_ws;
    int*   counts  = (int*)ws;                         // 32 B
    int*   offsets = (int*)(ws + 32);                  // 32 B
    int*   tsel    = (int*)(ws + 1024);                // 16 KB
    int*   ids     = (int*)(ws + 20480);               // 64 KB
    float* wts     = (float*)(ws + 90112);             // 64 KB
    unsigned short* h = (unsigned short*)(ws + 262144);        // 33.55 MB
    float* y       = (float*)(ws + 262144 + 33554432);         // 2 x 16.78 MB

    hipMemsetAsync(counts, 0, 8 * sizeof(int), stream);

    router_kernel<<<T_TOK / 4, 256, 0, stream>>>(x, rw, logits, counts, ids, wts, tsel);
    scan_kernel<<<1, 64, 0, stream>>>(counts, offsets);
    gemm_gu<<<dim3(INTER / 128, 16, NEXP), 512, 0, stream>>>(x, gw, uw, counts, offsets, ids, h);
    gemm_down<<<dim3(HIDDEN / 128, 16, NEXP * 2), 512, 0, stream>>>(h, dw, counts, offsets, wts, y);
    combine_kernel<<<T_TOK, 256, 0, stream>>>(y, offsets, tsel, out);
}

// Round 11
// 294.241 us; speedup vs baseline: 1.0717x; 1.0717x over previous
//
#include <hip/hip_runtime.h>
#include <hip/hip_bf16.h>

#define HIDDEN 1024
#define INTER 4096
#define NEXP 8
#define T_TOK 2048

typedef short bf16x8 __attribute__((ext_vector_type(8)));
typedef float f32x4 __attribute__((ext_vector_type(4)));

// Conflict-free BK=32 LDS chunk layout (R7/R8/R9-verified on HW: conflicts=0).
#define CHUNK(row, kq) ((unsigned int)((row) * 64u + ((((unsigned int)(kq)) ^ ((((unsigned int)(row)) >> 1) & 3u)) << 4)))

__device__ __forceinline__ unsigned short f2bf(float f) {
    union { float f; unsigned int u; } v; v.f = f;
    return (unsigned short)(v.u >> 16);   // truncation: 10x absmax margin measured
}

// two float4 -> one 16B chunk of 8 bf16 (truncating)
__device__ __forceinline__ uint4 pack8trunc(float4 a, float4 b) {
    union { float4 f; unsigned short s[8]; } x, y; x.f = a; y.f = b;
    uint4 r;
    r.x = (unsigned int)x.s[1] | ((unsigned int)x.s[3] << 16);
    r.y = (unsigned int)x.s[5] | ((unsigned int)x.s[7] << 16);
    r.z = (unsigned int)y.s[1] | ((unsigned int)y.s[3] << 16);
    r.w = (unsigned int)y.s[5] | ((unsigned int)y.s[7] << 16);
    return r;
}

// raw barrier: NO vmcnt drain (global prefetch stays in flight across it).
__device__ __forceinline__ void block_sync() {
    asm volatile("s_waitcnt lgkmcnt(0)" ::: "memory");
    __builtin_amdgcn_s_barrier();
    asm volatile("" ::: "memory");
}

// ---------------- K1: router (fp32 exact) ----------------
__global__ void router_kernel(const float* __restrict__ x,
                              const float* __restrict__ rw,
                              float* __restrict__ logits_out,
                              int* __restrict__ counts,
                              int* __restrict__ ids,
                              float* __restrict__ wts,
                              int* __restrict__ tsel) {
    int t = blockIdx.x * 4 + (threadIdx.x >> 6);
    int lane = threadIdx.x & 63;
    if (t >= T_TOK) return;
    const float4* xr = (const float4*)(x + (size_t)t * HIDDEN);
    float acc[NEXP];
#pragma unroll
    for (int e = 0; e < NEXP; e++) acc[e] = 0.f;
#pragma unroll
    for (int c = 0; c < 4; c++) {
        float4 xv = xr[lane + c * 64];
#pragma unroll
        for (int e = 0; e < NEXP; e++) {
            float4 wv = ((const float4*)(rw + (size_t)e * HIDDEN))[lane + c * 64];
            acc[e] += xv.x * wv.x + xv.y * wv.y + xv.z * wv.z + xv.w * wv.w;
        }
    }
#pragma unroll
    for (int e = 0; e < NEXP; e++) {
        float v = acc[e];
        for (int off = 32; off >= 1; off >>= 1) v += __shfl_xor(v, off, 64);
        acc[e] = v;
    }
    if (lane == 0) {
        float* lo = logits_out + (size_t)t * NEXP;
        float mx = acc[0];
#pragma unroll
        for (int e = 1; e < NEXP; e++) mx = fmaxf(mx, acc[e]);
        float p[NEXP], s = 0.f;
#pragma unroll
        for (int e = 0; e < NEXP; e++) { p[e] = __expf(acc[e] - mx); s += p[e]; }
        float inv = 1.f / s;
#pragma unroll
        for (int e = 0; e < NEXP; e++) { p[e] *= inv; lo[e] = acc[e]; }
        int i1 = 0;
#pragma unroll
        for (int e = 1; e < NEXP; e++) if (p[e] > p[i1]) i1 = e;
        int i2 = (i1 == 0) ? 1 : 0;
#pragma unroll
        for (int e = 0; e < NEXP; e++) if (e != i1 && e != i2 && p[e] > p[i2]) i2 = e;
        // strict > keeps lowest index on ties (matches jax top_k)
        int s1 = atomicAdd(&counts[i1], 1);
        ids[i1 * T_TOK + s1] = t; wts[i1 * T_TOK + s1] = p[i1];
        int s2 = atomicAdd(&counts[i2], 1);
        ids[i2 * T_TOK + s2] = t; wts[i2 * T_TOK + s2] = p[i2];
        tsel[t * 2]     = i1 * T_TOK + s1;   // pack (expert, slot)
        tsel[t * 2 + 1] = i2 * T_TOK + s2;
    }
}

__global__ void scan_kernel(const int* __restrict__ counts, int* __restrict__ offsets) {
    if (threadIdx.x == 0) {
        int s = 0;
        for (int e = 0; e < NEXP; e++) { offsets[e] = s; s += counts[e]; }
    }
}

// ---------------- K2: fused gate+up grouped GEMM + SwiGLU ----------------
// R9 geometry: BM=256 x BN=128, BK=32, 1024 thr (16 waves 4x4, wave 64x32
// per matrix), CHUNK LDS, raw barrier, 1-deep reg staging.
// R11 change: TWO separate __shared__ arrays (compiler-provable no-alias) +
// static x2 unroll + A-frag reads hoisted to region top. The ds_reads of the
// sealed buffer now overlap the vmcnt-wait/pack/ds_write of the other buffer
// instead of serializing behind them (single-array runtime offsets forced
// may-alias ordering in R6-R10).
__global__ __launch_bounds__(1024) void gemm_gu(
    const float* __restrict__ x, const float* __restrict__ gw, const float* __restrict__ uw,
    const int* __restrict__ counts, const int* __restrict__ offsets,
    const int* __restrict__ ids, unsigned short* __restrict__ h) {
    const int e = blockIdx.z;
    const int cnt = counts[e];
    const int mt = blockIdx.y;
    if (mt * 256 >= cnt) return;
    const int nt = blockIdx.x;                    // 32 tiles of 128 inter
    const int tid = threadIdx.x;
    const int lane = tid & 63, wid = tid >> 6;
    const int wm = wid >> 2, wn = wid & 3;        // 4x4 waves

    __shared__ __align__(16) char bufE[32768];    // [A 16K | Bg 8K | Bu 8K]
    __shared__ __align__(16) char bufO[32768];

    // A: 256 rows x 4 chunks = 1024; one per thread (2 float4 -> 1 chunk)
    const int arow = tid >> 2, akq = tid & 3;
    int ali = mt * 256 + arow; if (ali >= cnt) ali = cnt - 1;
    const unsigned int aoff = (unsigned int)(ids[e * T_TOK + ali] * HIDDEN + akq * 8);
    const unsigned int wAo = CHUNK(arow, akq);
    // B: 512 g-chunks + 512 u-chunks = 1024; one per thread
    const int bsel = tid >> 9;                    // 0 = gate, 1 = up
    const int bi = tid & 511;
    const int brow = bi >> 2, bkq = bi & 3;
    const float* bsrc = (bsel ? uw : gw) + (size_t)e * INTER * HIDDEN
                        + (size_t)(nt * 128 + brow) * HIDDEN + bkq * 8;
    const unsigned int wBo = 16384u + ((unsigned int)bsel << 13) + CHUNK(brow, bkq);

    f32x4 accg[4][2], accu[4][2];
#pragma unroll
    for (int mf = 0; mf < 4; mf++)
#pragma unroll
        for (int nf = 0; nf < 2; nf++)
#pragma unroll
            for (int v = 0; v < 4; v++) { accg[mf][nf][v] = 0.f; accu[mf][nf][v] = 0.f; }

    // 1-deep reg staging (16 VGPRs), same budget as R9
    float4 s0, s1, t0, t1;
    s0 = *(const float4*)(x + aoff); s1 = *(const float4*)(x + aoff + 4);
    t0 = *(const float4*)(bsrc);     t1 = *(const float4*)(bsrc + 4);
    // seal tile 0 into bufE
    *(uint4*)(bufE + wAo) = pack8trunc(s0, s1);
    *(uint4*)(bufE + wBo) = pack8trunc(t0, t1);
    // tile 1 into staging regs
    s0 = *(const float4*)(x + aoff + 32); s1 = *(const float4*)(x + aoff + 36);
    t0 = *(const float4*)(bsrc + 32);     t1 = *(const float4*)(bsrc + 36);
    block_sync();

    const unsigned int kqr = (unsigned int)(lane >> 4);
    const unsigned int rl = (unsigned int)(lane & 15);

    // Body KT: reads tile KT from RB (sealed); writes tile KT+1 to WB;
    // issues loads for tile KT+2; MFMA; one barrier.
#define GU_BODY(KT, RB, WB)                                                             \
    {                                                                                   \
        bf16x8 fa[4];                                                                   \
        _Pragma("unroll")                                                               \
        for (int mf = 0; mf < 4; mf++)                                                  \
            fa[mf] = *(const bf16x8*)((RB) + CHUNK(wm * 64 + mf * 16 + rl, kqr));       \
        if ((KT) + 1 < 32) {                                                            \
            *(uint4*)((WB) + wAo) = pack8trunc(s0, s1);                                 \
            *(uint4*)((WB) + wBo) = pack8trunc(t0, t1);                                 \
        }                                                                               \
        if ((KT) + 2 < 32) {                                                            \
            const int ko = ((KT) + 2) * 32;                                             \
            s0 = *(const float4*)(x + aoff + ko); s1 = *(const float4*)(x + aoff + ko + 4); \
            t0 = *(const float4*)(bsrc + ko);     t1 = *(const float4*)(bsrc + ko + 4); \
        }                                                                               \
        _Pragma("unroll")                                                               \
        for (int nf = 0; nf < 2; nf++) {                                                \
            const unsigned int br = wn * 32 + nf * 16 + rl;                             \
            bf16x8 bg = *(const bf16x8*)((RB) + 16384 + CHUNK(br, kqr));                \
            bf16x8 bu = *(const bf16x8*)((RB) + 24576 + CHUNK(br, kqr));                \
            _Pragma("unroll")                                                           \
            for (int mf = 0; mf < 4; mf++) {                                            \
                accg[mf][nf] = __builtin_amdgcn_mfma_f32_16x16x32_bf16(fa[mf], bg, accg[mf][nf], 0, 0, 0); \
                accu[mf][nf] = __builtin_amdgcn_mfma_f32_16x16x32_bf16(fa[mf], bu, accu[mf][nf], 0, 0, 0); \
            }                                                                           \
        }                                                                               \
        block_sync();                                                                   \
    }

    for (int kt = 0; kt < 32; kt += 2) {
        GU_BODY(kt, bufE, bufO)
        GU_BODY(kt + 1, bufO, bufE)
    }
#undef GU_BODY

    const int hoff = offsets[e];
#pragma unroll
    for (int mf = 0; mf < 4; mf++)
#pragma unroll
        for (int v = 0; v < 4; v++) {
            int il = wm * 64 + mf * 16 + ((lane >> 4) << 2) + v;
            int i = mt * 256 + il;
            if (i < cnt) {
                size_t rowbase = (size_t)(hoff + i) * INTER + nt * 128 + wn * 32 + (lane & 15);
#pragma unroll
                for (int nf = 0; nf < 2; nf++) {
                    float g = accg[mf][nf][v], u = accu[mf][nf][v];
                    float sg = g / (1.f + __expf(-g));
                    h[rowbase + nf * 16] = f2bf(sg * u);
                }
            }
        }
}

// ---------------- K3: down grouped GEMM -> y (no atomics) ----------------
// R9 geometry: BM=128 x BN=128, BK=32, ksplit=2, 512 thr (8 waves 2x4, wave
// 64x32), CHUNK LDS, 1-deep staging. R11 change: same no-alias two-array
// static-unroll pipeline as gemm_gu.
__global__ __launch_bounds__(512) void gemm_down(
    const unsigned short* __restrict__ h, const float* __restrict__ dw,
    const int* __restrict__ counts, const int* __restrict__ offsets,
    const float* __restrict__ wts, float* __restrict__ y) {
    const int ez = blockIdx.z;                    // e*2 + ksp
    const int e = ez >> 1, ksp = ez & 1;
    const int cnt = counts[e];
    const int mt = blockIdx.y;
    if (mt * 128 >= cnt) return;
    const int nt = blockIdx.x;                    // 8 tiles of 128 hidden
    const int tid = threadIdx.x;
    const int lane = tid & 63, wid = tid >> 6;
    const int wm = wid >> 2, wn = wid & 3;        // 2x4 waves, wave 64x32

    __shared__ __align__(16) char bufE[16384];    // [A 8K | B 8K]
    __shared__ __align__(16) char bufO[16384];

    const int hoff = offsets[e];
    const float* dbase = dw + (size_t)e * HIDDEN * INTER;

    // A (h, bf16): 128 rows x 4 chunks = 512; one per thread (direct int4)
    const int row = tid >> 2, kq = tid & 3;
    int li = mt * 128 + row; if (li >= cnt) li = cnt - 1;
    const unsigned int aoff = (unsigned int)((hoff + li) * INTER + ksp * 2048 + kq * 8);
    const unsigned int wAo = CHUNK(row, kq);
    // B (dw, fp32): 128 rows x 4 chunks = 512; one per thread (2 float4)
    const unsigned int boff = (unsigned int)((nt * 128 + row) * INTER + ksp * 2048 + kq * 8);
    const unsigned int wBo = 8192u + CHUNK(row, kq);

    f32x4 acc[4][2];
#pragma unroll
    for (int mf = 0; mf < 4; mf++)
#pragma unroll
        for (int nf = 0; nf < 2; nf++)
#pragma unroll
            for (int v = 0; v < 4; v++) acc[mf][nf][v] = 0.f;

    int4 av; float4 b0, b1;
    av = *(const int4*)(h + aoff);
    b0 = *(const float4*)(dbase + boff); b1 = *(const float4*)(dbase + boff + 4);
    *(int4*)(bufE + wAo) = av;
    *(uint4*)(bufE + wBo) = pack8trunc(b0, b1);
    av = *(const int4*)(h + aoff + 32);
    b0 = *(const float4*)(dbase + boff + 32); b1 = *(const float4*)(dbase + boff + 36);
    block_sync();

    const unsigned int kqr = (unsigned int)(lane >> 4);
    const unsigned int rl = (unsigned int)(lane & 15);

#define DN_BODY(KT, RB, WB)                                                             \
    {                                                                                   \
        bf16x8 fa[4];                                                                   \
        _Pragma("unroll")                                                               \
        for (int mf = 0; mf < 4; mf++)                                                  \
            fa[mf] = *(const bf16x8*)((RB) + CHUNK(wm * 64 + mf * 16 + rl, kqr));       \
        if ((KT) + 1 < 64) {                                                            \
            *(int4*)((WB) + wAo) = av;                                                  \
            *(uint4*)((WB) + wBo) = pack8trunc(b0, b1);                                 \
        }                                                                               \
        if ((KT) + 2 < 64) {                                                            \
            const int ko = ((KT) + 2) * 32;                                             \
            av = *(const int4*)(h + aoff + ko);                                         \
            b0 = *(const float4*)(dbase + boff + ko); b1 = *(const float4*)(dbase + boff + ko + 4); \
        }                                                                               \
        _Pragma("unroll")                                                               \
        for (int nf = 0; nf < 2; nf++) {                                                \
            bf16x8 b = *(const bf16x8*)((RB) + 8192 + CHUNK(wn * 32 + nf * 16 + rl, kqr)); \
            _Pragma("unroll")                                                           \
            for (int mf = 0; mf < 4; mf++)                                              \
                acc[mf][nf] = __builtin_amdgcn_mfma_f32_16x16x32_bf16(fa[mf], b, acc[mf][nf], 0, 0, 0); \
        }                                                                               \
        block_sync();                                                                   \
    }

    for (int kt = 0; kt < 64; kt += 2) {          // 2048 K per split
        DN_BODY(kt, bufE, bufO)
        DN_BODY(kt + 1, bufO, bufE)
    }
#undef DN_BODY

#pragma unroll
    for (int mf = 0; mf < 4; mf++)
#pragma unroll
        for (int v = 0; v < 4; v++) {
            int il = wm * 64 + mf * 16 + ((lane >> 4) << 2) + v;
            int i = mt * 128 + il;
            if (i < cnt) {
                float w = wts[e * T_TOK + i];
                float* yrow = y + ((size_t)ksp * 4096 + hoff + i) * HIDDEN
                                + nt * 128 + wn * 32 + (lane & 15);
#pragma unroll
                for (int nf = 0; nf < 2; nf++)
                    yrow[nf * 16] = w * acc[mf][nf][v];
            }
        }
}

// -------- K4: combine (out[t] = sum over 2 experts x 2 ksplits) --------
__global__ __launch_bounds__(256) void combine_kernel(
    const float* __restrict__ y, const int* __restrict__ offsets,
    const int* __restrict__ tsel, float* __restrict__ out) {
    const int t = blockIdx.x;
    const int d = threadIdx.x * 4;
    int p0 = tsel[t * 2], p1 = tsel[t * 2 + 1];
    size_t g0 = (size_t)(offsets[p0 >> 11] + (p0 & (T_TOK - 1)));
    size_t g1 = (size_t)(offsets[p1 >> 11] + (p1 & (T_TOK - 1)));
    float4 a0 = *(const float4*)(y + g0 * HIDDEN + d);
    float4 a1 = *(const float4*)(y + (4096 + g0) * HIDDEN + d);
    float4 b0 = *(const float4*)(y + g1 * HIDDEN + d);
    float4 b1 = *(const float4*)(y + (4096 + g1) * HIDDEN + d);
    float4 o;
    o.x = (a0.x + a1.x) + (b0.x + b1.x);
    o.y = (a0.y + a1.y) + (b0.y + b1.y);
    o.z = (a0.z + a1.z) + (b0.z + b1.z);
    o.w = (a0.w + a1.w) + (b0.w + b1.w);
    *(float4*)(out + (size_t)t * HIDDEN + d) = o;
}

extern "C" void kernel_launch(void* const* d_in, const int* in_sizes, int n_in,
                              void* d_out, int out_size, void* d_ws, size_t ws_size,
                              hipStream_t stream) {
    const float* x  = (const float*)d_in[0];
    const float* rw = (const float*)d_in[1];
    const float* gw = (const float*)d_in[2];
    const float* uw = (const float*)d_in[3];
    const float* dw = (const float*)d_in[4];
    float* out = (float*)d_out;
    float* logits = out + (size_t)T_TOK * HIDDEN;

    char* ws = (char*)d_ws;
    int*   counts  = (int*)ws;                         // 32 B
    int*   offsets = (int*)(ws + 32);                  // 32 B
    int*   tsel    = (int*)(ws + 1024);                // 16 KB
    int*   ids     = (int*)(ws + 20480);               // 64 KB
    float* wts     = (float*)(ws + 90112);             // 64 KB
    unsigned short* h = (unsigned short*)(ws + 262144);        // 33.55 MB
    float* y       = (float*)(ws + 262144 + 33554432);         // 2 x 16.78 MB

    hipMemsetAsync(counts, 0, 8 * sizeof(int), stream);

    router_kernel<<<T_TOK / 4, 256, 0, stream>>>(x, rw, logits, counts, ids, wts, tsel);
    scan_kernel<<<1, 64, 0, stream>>>(counts, offsets);
    gemm_gu<<<dim3(INTER / 128, 8, NEXP), 1024, 0, stream>>>(x, gw, uw, counts, offsets, ids, h);
    gemm_down<<<dim3(HIDDEN / 128, 16, NEXP * 2), 512, 0, stream>>>(h, dw, counts, offsets, wts, y);
    combine_kernel<<<T_TOK, 256, 0, stream>>>(y, offsets, tsel, out);
}